// Round 5
// baseline (503.927 us; speedup 1.0000x reference)
//
#include <hip/hip_runtime.h>
#include <math.h>

namespace {

constexpr int SB = 2, NV = 4, N = 512, L = 256, H = 128, W = 128;
constexpr int PAD = 5, NP = 11, K = 121;   // padding fixed at 5 by setup_inputs
constexpr int PS = 16;                      // 16x16 patch, origin floor(center)-6
constexpr int HW = H * W;
constexpr int MAPST = 8;                    // 8 fp64 per pixel record (64 B, line-aligned)
constexpr float IMG = 128.0f;

typedef float f4v __attribute__((ext_vector_type(4), aligned(4)));  // 4B-aligned float4
typedef float f2v __attribute__((ext_vector_type(2), aligned(4)));  // 4B-aligned float2

// Reference coordinate math: t = clip((g+1)*0.5*(size-1), 0, size-1),
// i0 = floor(t), w = t - i0, i1 = min(i0+1, size-1).
__device__ __forceinline__ void coord1(float gn, int size, int& i0, int& i1, float& w) {
    float t = (gn + 1.0f) * 0.5f * (float)(size - 1);
    t = fminf(fmaxf(t, 0.0f), (float)(size - 1));
    float f = floorf(t);
    i0 = (int)f;
    i1 = min(i0 + 1, size - 1);
    w = t - f;
}

// Per-image, per-pixel maps (point-invariant): for pixel p=(y,x) with clamped
// neighbors xn=(y,min(x+1,W-1)), dn=(min(y+1,H-1),x), dg=(min(y+1),min(x+1)):
//   S2=sum_c P*P, SH=sum_c P*Pxn, SV=sum_c P*Pdn, SD=sum_c P*Pdg, SA=sum_c Pxn*Pdn.
// fp64 fma in c order 0..255 — bit-identical to the previous per-point chains.
// Record layout: maps[(imC*HW + y*W + x)*MAPST + {0:S2,1:SH,2:SV,3:SD,4:SA}].
__global__ __launch_bounds__(64) void map_kernel(const float* __restrict__ latent,
                                                 double* __restrict__ maps) {
    const int b   = blockIdx.x;          // imC*H + r
    const int imC = b >> 7, r = b & 127;
    const int sb  = imC / 3, v = imC % 3;
    const int ln  = threadIdx.x;         // lane owns cols 2ln, 2ln+1
    const float* base = latent + (size_t)(sb * NV + 1 + v) * L * HW;
    const float* rowA = base + r * W + 2 * ln;
    const float* rowB = base + min(r + 1, H - 1) * W + 2 * ln;

    double s2a = 0, s2b = 0, sha = 0, shb = 0, sva = 0, svb = 0;
    double sda = 0, sdb = 0, saa = 0, sab = 0;
    #pragma unroll 4
    for (int c = 0; c < L; ++c) {
        const f2v A  = *reinterpret_cast<const f2v*>(rowA + (size_t)c * HW);
        const f2v Bv = *reinterpret_cast<const f2v*>(rowB + (size_t)c * HW);
        float xn1 = __shfl(A.x, ln + 1, 64);   // col 2ln+2 (next lane's .x)
        float dg1 = __shfl(Bv.x, ln + 1, 64);
        if (ln == 63) { xn1 = A.y; dg1 = Bv.y; }   // col 127: clamp(128)=127 -> self
        // pixel a: col 2ln  -> p=A.x  xn=A.y  dn=Bv.x dg=Bv.y
        // pixel b: col 2ln+1-> p=A.y  xn=xn1  dn=Bv.y dg=dg1
        const double pa = A.x, xa = A.y, na = Bv.x, ga = Bv.y;
        const double pb = A.y, xb = xn1, nb = Bv.y, gb = dg1;
        s2a = fma(pa, pa, s2a); s2b = fma(pb, pb, s2b);
        sha = fma(pa, xa, sha); shb = fma(pb, xb, shb);
        sva = fma(pa, na, sva); svb = fma(pb, nb, svb);
        sda = fma(pa, ga, sda); sdb = fma(pb, gb, sdb);
        saa = fma(xa, na, saa); sab = fma(xb, nb, sab);
    }
    double* ra = maps + (size_t)(imC * HW + r * W + 2 * ln) * MAPST;
    ra[0] = s2a; ra[1] = sha; ra[2] = sva; ra[3] = sda; ra[4] = saa;
    double* rb = ra + MAPST;
    rb[0] = s2b; rb[1] = shb; rb[2] = svb; rb[3] = sdb; rb[4] = sab;
}

// One wave per (sb, n): lane handles 4 channels; float2 taps (v00,v01)/(v10,v11).
__global__ __launch_bounds__(64) void ref_kernel(const float* __restrict__ uv,
        const float* __restrict__ latent, const float* __restrict__ ls,
        float* __restrict__ out, float* __restrict__ ref_pm) {
    const int pidx = blockIdx.x;           // sb*N + n
    const int sb = pidx / N, n = pidx % N;
    const int ln = threadIdx.x;
    const float sx = ls[0] / IMG, sy = ls[1] / IMG;
    const float2 uvp = reinterpret_cast<const float2*>(uv)[(sb * NV + 0) * N + n];
    int x0, x1, y0, y1; float wx, wy;
    coord1(uvp.x * sx - 1.0f, W, x0, x1, wx);
    coord1(uvp.y * sy - 1.0f, H, y0, y1, wy);
    const float* img = latent + (size_t)(sb * NV + 0) * L * HW;
    float* o  = out + (size_t)(sb * NV + 0) * L * N + n;
    float* rp = ref_pm + (size_t)pidx * L;
    if (x0 + 1 < W) {                      // wave-uniform fast path
        const float* t0 = img + y0 * W + x0;
        const float* b0 = img + y1 * W + x0;
        #pragma unroll
        for (int it = 0; it < 4; ++it) {
            const int c = it * 64 + ln;
            const f2v tv = *reinterpret_cast<const f2v*>(t0 + (size_t)c * HW);
            const f2v bv = *reinterpret_cast<const f2v*>(b0 + (size_t)c * HW);
            const float top = tv.x * (1.0f - wx) + tv.y * wx;
            const float bot = bv.x * (1.0f - wx) + bv.y * wx;
            const float val = top * (1.0f - wy) + bot * wy;
            o[(size_t)c * N] = val;
            rp[c] = val;
        }
    } else {
        #pragma unroll
        for (int it = 0; it < 4; ++it) {
            const int c = it * 64 + ln;
            const float* ch = img + (size_t)c * HW;
            const float v00 = ch[y0 * W + x0], v01 = ch[y0 * W + x1];
            const float v10 = ch[y1 * W + x0], v11 = ch[y1 * W + x1];
            const float top = v00 * (1.0f - wx) + v01 * wx;
            const float bot = v10 * (1.0f - wx) + v11 * wx;
            const float val = top * (1.0f - wy) + bot * wy;
            o[(size_t)c * N] = val;
            rp[c] = val;
        }
    }
}

// One wave per (sb, warp-view, point). Lane (r=ln>>2, q=ln&3) owns patch row r,
// cols 4q..4q+3 (float4). Only the point-dependent R map is accumulated here.
__global__ __launch_bounds__(64) void warp_kernel(const float* __restrict__ uv,
        const float* __restrict__ latent, const float* __restrict__ ls,
        float* __restrict__ out, const float* __restrict__ ref_pm,
        const double* __restrict__ maps) {
    const int bid = blockIdx.x;
    const int sb  = bid / ((NV - 1) * N);
    const int rem = bid % ((NV - 1) * N);
    const int v   = rem / N;
    const int n   = rem % N;
    const int imC = sb * 3 + v;
    const int ln  = threadIdx.x;
    const int r   = ln >> 2, q = ln & 3;

    __shared__ double mRl[PS * 17];   // [16][17] padded: row byte-stride 136 rotates banks

    const float ls0 = ls[0], ls1 = ls[1];
    const float sx = ls0 / IMG, sy = ls1 / IMG;
    const float2 uvp = reinterpret_cast<const float2*>(uv)[(sb * NV + 1 + v) * N + n];
    const float uvnx = uvp.x * sx - 1.0f;
    const float uvny = uvp.y * sy - 1.0f;
    const float txc = fminf(fmaxf((uvnx + 1.0f) * 0.5f * (float)(W - 1), 0.0f), (float)(W - 1));
    const float tyc = fminf(fmaxf((uvny + 1.0f) * 0.5f * (float)(H - 1), 0.0f), (float)(H - 1));
    const int ox = (int)floorf(txc) - 6;
    const int oy = (int)floorf(tyc) - 6;

    const float* lat  = latent + (size_t)(sb * NV + 1 + v) * L * HW;
    const float* refp = ref_pm + (size_t)(sb * N + n) * L;
    const double* mimg = maps + (size_t)imC * HW * MAPST;

    const int gy = min(max(oy + r, 0), H - 1);      // border-clamped row
    const int cb = ox + 4 * q;
    const bool fast = (ox >= 0) && (ox + PS <= W);
    const int gx0 = min(max(cb + 0, 0), W - 1);
    const int gx1 = min(max(cb + 1, 0), W - 1);
    const int gx2 = min(max(cb + 2, 0), W - 1);
    const int gx3 = min(max(cb + 3, 0), W - 1);
    const float* rowp = lat + (size_t)gy * W;

    double aR[4] = {0, 0, 0, 0};
    if (fast) {
        const float* pbase = rowp + cb;
        #pragma unroll 4
        for (int c = 0; c < L; ++c) {
            const f4v p = *reinterpret_cast<const f4v*>(pbase + (size_t)c * HW);
            const double rf = (double)refp[c];
            aR[0] = fma(rf, (double)p.x, aR[0]);
            aR[1] = fma(rf, (double)p.y, aR[1]);
            aR[2] = fma(rf, (double)p.z, aR[2]);
            aR[3] = fma(rf, (double)p.w, aR[3]);
        }
    } else {
        #pragma unroll 4
        for (int c = 0; c < L; ++c) {
            const float* chp = rowp + (size_t)c * HW;
            const double rf = (double)refp[c];
            aR[0] = fma(rf, (double)chp[gx0], aR[0]);
            aR[1] = fma(rf, (double)chp[gx1], aR[1]);
            aR[2] = fma(rf, (double)chp[gx2], aR[2]);
            aR[3] = fma(rf, (double)chp[gx3], aR[3]);
        }
    }
    const int mi = r * 17 + 4 * q;
    mRl[mi + 0] = aR[0]; mRl[mi + 1] = aR[1]; mRl[mi + 2] = aR[2]; mRl[mi + 3] = aR[3];
    __syncthreads();

    auto scoreOf = [&](int k) -> double {
        const int i = k / NP, j = k % NP;          // i -> x offset, j -> y offset
        const float gpx = ((float)(i - PAD) / (float)W) * ls0;
        const float gpy = ((float)(j - PAD) / (float)H) * ls1;
        int x0, x1, y0, y1; float wx, wy;
        coord1(uvnx + gpx, W, x0, x1, wx);
        coord1(uvny + gpy, H, y0, y1, wy);
        // R (point-dependent) from LDS patch; clamped staging folds x1/y1 borders.
        const int cx0 = min(max(x0 - ox, 0), 15), cx1 = min(max(x1 - ox, 0), 15);
        const int cy0 = min(max(y0 - oy, 0), 15), cy1 = min(max(y1 - oy, 0), 15);
        const double R00 = mRl[cy0 * 17 + cx0], R01 = mRl[cy0 * 17 + cx1];
        const double R10 = mRl[cy1 * 17 + cx0], R11 = mRl[cy1 * 17 + cx1];
        // Point-invariant maps from global (L2-resident records, 64B each).
        const double* r00 = mimg + (size_t)(y0 * W + x0) * MAPST;
        const double* r01 = mimg + (size_t)(y0 * W + x1) * MAPST;
        const double* r10 = mimg + (size_t)(y1 * W + x0) * MAPST;
        const double* r11 = mimg + (size_t)(y1 * W + x1) * MAPST;
        const double dwx = (double)wx, dwy = (double)wy;
        const double Aw = (1.0 - dwy) * (1.0 - dwx), Bw = (1.0 - dwy) * dwx;
        const double Cw = dwy * (1.0 - dwx),         Dw = dwy * dwx;
        const double num = (1.0 - dwy) * ((1.0 - dwx) * R00 + dwx * R01)
                         +        dwy  * ((1.0 - dwx) * R10 + dwx * R11);
        double nrm = Aw * Aw * r00[0] + Bw * Bw * r01[0]
                   + Cw * Cw * r10[0] + Dw * Dw * r11[0]
                   + 2.0 * (Aw * Bw * r00[1] + Cw * Dw * r10[1]
                          + Aw * Cw * r00[2] + Bw * Dw * r01[2]
                          + Aw * Dw * r00[3] + Bw * Cw * r00[4]);
        nrm = fmax(nrm, 0.0);
        return num / fmax(sqrt(nrm), 1.0e-8);      // ref-norm is a positive per-point constant
    };

    double bs = scoreOf(ln);                        // lanes 0..63 all < K
    int    bi = ln;
    if (ln + 64 < K) {
        const double s2 = scoreOf(ln + 64);
        if (s2 > bs) { bs = s2; bi = ln + 64; }     // strict >: smaller k wins ties
    }
    #pragma unroll
    for (int d = 1; d < 64; d <<= 1) {
        const double so = __shfl_xor(bs, d, 64);
        const int    io = __shfl_xor(bi, d, 64);
        if (so > bs || (so == bs && io < bi)) { bs = so; bi = io; }
    }
    const int ksel = bi;

    // Phase 2: exact reference resample of the winner; lane handles 4 channels.
    const int si = ksel / NP, sj = ksel % NP;
    const float gpx = ((float)(si - PAD) / (float)W) * ls0;
    const float gpy = ((float)(sj - PAD) / (float)H) * ls1;
    int x0, x1, y0, y1; float wx, wy;
    coord1(uvnx + gpx, W, x0, x1, wx);
    coord1(uvny + gpy, H, y0, y1, wy);
    float* o = out + (size_t)((sb * NV + 1 + v) * L) * N + n;
    if (x0 + 1 < W) {                              // wave-uniform fast path
        const float* t0 = lat + y0 * W + x0;
        const float* b0 = lat + y1 * W + x0;
        #pragma unroll
        for (int it = 0; it < 4; ++it) {
            const int c = it * 64 + ln;
            const f2v tv = *reinterpret_cast<const f2v*>(t0 + (size_t)c * HW);
            const f2v bv = *reinterpret_cast<const f2v*>(b0 + (size_t)c * HW);
            const float top = tv.x * (1.0f - wx) + tv.y * wx;
            const float bot = bv.x * (1.0f - wx) + bv.y * wx;
            o[(size_t)c * N] = top * (1.0f - wy) + bot * wy;
        }
    } else {
        #pragma unroll
        for (int it = 0; it < 4; ++it) {
            const int c = it * 64 + ln;
            const float* ch = lat + (size_t)c * HW;
            const float v00 = ch[y0 * W + x0], v01 = ch[y0 * W + x1];
            const float v10 = ch[y1 * W + x0], v11 = ch[y1 * W + x1];
            const float top = v00 * (1.0f - wx) + v01 * wx;
            const float bot = v10 * (1.0f - wx) + v11 * wx;
            o[(size_t)c * N] = top * (1.0f - wy) + bot * wy;
        }
    }
}

} // namespace

extern "C" void kernel_launch(void* const* d_in, const int* in_sizes, int n_in,
                              void* d_out, int out_size, void* d_ws, size_t ws_size,
                              hipStream_t stream) {
    const float* uv     = (const float*)d_in[0];
    const float* latent = (const float*)d_in[1];
    const float* ls     = (const float*)d_in[2];
    float* out    = (float*)d_out;
    float* ref_pm = (float*)d_ws;                                   // 1 MB
    double* maps  = (double*)((char*)d_ws + (1 << 20));             // 6*16384*64B = 6.3 MB

    hipLaunchKernelGGL(map_kernel, dim3(6 * H), dim3(64), 0, stream, latent, maps);
    hipLaunchKernelGGL(ref_kernel, dim3(SB * N), dim3(64), 0, stream, uv, latent, ls, out, ref_pm);
    hipLaunchKernelGGL(warp_kernel, dim3(SB * (NV - 1) * N), dim3(64), 0, stream,
                       uv, latent, ls, out, ref_pm, maps);
}

// Round 6
// 487.153 us; speedup vs baseline: 1.0344x; 1.0344x over previous
//
#include <hip/hip_runtime.h>
#include <math.h>

namespace {

constexpr int SB = 2, NV = 4, N = 512, L = 256, H = 128, W = 128;
constexpr int PAD = 5, NP = 11, K = 121;   // padding fixed at 5 by setup_inputs
constexpr int PS = 16;                      // 16x16 patch, origin floor(center)-6
constexpr int HW = H * W;
constexpr int MAPST = 8;                    // 8 fp64 per pixel record (64 B, line-aligned)
constexpr float IMG = 128.0f;

typedef float f4v __attribute__((ext_vector_type(4), aligned(4)));  // 4B-aligned float4
typedef float f2v __attribute__((ext_vector_type(2), aligned(4)));  // 4B-aligned float2

// Reference coordinate math: t = clip((g+1)*0.5*(size-1), 0, size-1),
// i0 = floor(t), w = t - i0, i1 = min(i0+1, size-1).
__device__ __forceinline__ void coord1(float gn, int size, int& i0, int& i1, float& w) {
    float t = (gn + 1.0f) * 0.5f * (float)(size - 1);
    t = fminf(fmaxf(t, 0.0f), (float)(size - 1));
    float f = floorf(t);
    i0 = (int)f;
    i1 = min(i0 + 1, size - 1);
    w = t - f;
}

// Point-invariant per-pixel maps, channel-split over 4 waves + fixed-order reduce.
// For pixel p=(y,x) with clamped neighbors xn/dn/dg:
//   S2=sum P*P, SH=sum P*Pxn, SV=sum P*Pdn, SD=sum P*Pdg, SA=sum Pxn*Pdn.
// Record: maps[(imC*HW + y*W + x)*MAPST + {0:S2,1:SH,2:SV,3:SD,4:SA}].
__global__ __launch_bounds__(256) void map_kernel(const float* __restrict__ latent,
                                                  double* __restrict__ maps) {
    const int b  = blockIdx.x;
    const int wg = (b & 7) * 96 + (b >> 3);    // XCD swizzle (768 = 8*96, bijective)
    const int imC = wg >> 7, r = wg & 127;
    const int sb = imC / 3, v = imC % 3;
    const int t = threadIdx.x, wv = t >> 6, ln = t & 63;   // lane owns cols 2ln, 2ln+1

    __shared__ double part[4][64][10];

    const float* base = latent + (size_t)(sb * NV + 1 + v) * L * HW + (size_t)wv * 64 * HW;
    const float* rowA = base + r * W + 2 * ln;
    const float* rowB = base + min(r + 1, H - 1) * W + 2 * ln;

    double s[10] = {0, 0, 0, 0, 0, 0, 0, 0, 0, 0};
    #pragma unroll 4
    for (int c = 0; c < 64; ++c) {
        const f2v A  = *reinterpret_cast<const f2v*>(rowA + (size_t)c * HW);
        const f2v Bv = *reinterpret_cast<const f2v*>(rowB + (size_t)c * HW);
        float xn1 = __shfl(A.x, ln + 1, 64);   // col 2ln+2
        float dg1 = __shfl(Bv.x, ln + 1, 64);
        if (ln == 63) { xn1 = A.y; dg1 = Bv.y; }   // col 127: clamp(128)=127 -> self
        const double pa = A.x, xa = A.y, na = Bv.x, ga = Bv.y;   // pixel a = col 2ln
        const double pb = A.y, xb = xn1, nb = Bv.y, gb = dg1;    // pixel b = col 2ln+1
        s[0] = fma(pa, pa, s[0]); s[5] = fma(pb, pb, s[5]);
        s[1] = fma(pa, xa, s[1]); s[6] = fma(pb, xb, s[6]);
        s[2] = fma(pa, na, s[2]); s[7] = fma(pb, nb, s[7]);
        s[3] = fma(pa, ga, s[3]); s[8] = fma(pb, gb, s[8]);
        s[4] = fma(xa, na, s[4]); s[9] = fma(xb, nb, s[9]);
    }
    #pragma unroll
    for (int j = 0; j < 10; ++j) part[wv][ln][j] = s[j];
    __syncthreads();
    if (wv < 2) {                              // wave0 -> pixel a, wave1 -> pixel b
        const int off = wv * 5;
        double r0 = ((part[0][ln][off+0] + part[1][ln][off+0]) + part[2][ln][off+0]) + part[3][ln][off+0];
        double r1 = ((part[0][ln][off+1] + part[1][ln][off+1]) + part[2][ln][off+1]) + part[3][ln][off+1];
        double r2 = ((part[0][ln][off+2] + part[1][ln][off+2]) + part[2][ln][off+2]) + part[3][ln][off+2];
        double r3 = ((part[0][ln][off+3] + part[1][ln][off+3]) + part[2][ln][off+3]) + part[3][ln][off+3];
        double r4 = ((part[0][ln][off+4] + part[1][ln][off+4]) + part[2][ln][off+4]) + part[3][ln][off+4];
        double* ra = maps + (size_t)(imC * HW + r * W + 2 * ln + wv) * MAPST;
        ra[0] = r0; ra[1] = r1; ra[2] = r2; ra[3] = r3; ra[4] = r4;
    }
}

// One wave per (sb, n): lane handles 4 channels; float2 taps.
__global__ __launch_bounds__(64) void ref_kernel(const float* __restrict__ uv,
        const float* __restrict__ latent, const float* __restrict__ ls,
        float* __restrict__ out, float* __restrict__ ref_pm) {
    const int pidx = blockIdx.x;           // sb*N + n
    const int sb = pidx / N, n = pidx % N;
    const int ln = threadIdx.x;
    const float sx = ls[0] / IMG, sy = ls[1] / IMG;
    const float2 uvp = reinterpret_cast<const float2*>(uv)[(sb * NV + 0) * N + n];
    int x0, x1, y0, y1; float wx, wy;
    coord1(uvp.x * sx - 1.0f, W, x0, x1, wx);
    coord1(uvp.y * sy - 1.0f, H, y0, y1, wy);
    const float* img = latent + (size_t)(sb * NV + 0) * L * HW;
    float* o  = out + (size_t)(sb * NV + 0) * L * N + n;
    float* rp = ref_pm + (size_t)pidx * L;
    if (x0 + 1 < W) {                      // wave-uniform fast path
        const float* t0 = img + y0 * W + x0;
        const float* b0 = img + y1 * W + x0;
        #pragma unroll
        for (int it = 0; it < 4; ++it) {
            const int c = it * 64 + ln;
            const f2v tv = *reinterpret_cast<const f2v*>(t0 + (size_t)c * HW);
            const f2v bv = *reinterpret_cast<const f2v*>(b0 + (size_t)c * HW);
            const float top = tv.x * (1.0f - wx) + tv.y * wx;
            const float bot = bv.x * (1.0f - wx) + bv.y * wx;
            const float val = top * (1.0f - wy) + bot * wy;
            o[(size_t)c * N] = val;
            rp[c] = val;
        }
    } else {
        #pragma unroll
        for (int it = 0; it < 4; ++it) {
            const int c = it * 64 + ln;
            const float* ch = img + (size_t)c * HW;
            const float v00 = ch[y0 * W + x0], v01 = ch[y0 * W + x1];
            const float v10 = ch[y1 * W + x0], v11 = ch[y1 * W + x1];
            const float top = v00 * (1.0f - wx) + v01 * wx;
            const float bot = v10 * (1.0f - wx) + v11 * wx;
            const float val = top * (1.0f - wy) + bot * wy;
            o[(size_t)c * N] = val;
            rp[c] = val;
        }
    }
}

// One 256-thread block per (sb, warp-view, point). Each of 4 waves accumulates
// R-partials for 64 channels; lane (r=ln>>2, q=ln&3) owns patch row r, cols
// 4q..4q+3 (one dwordx4 per channel). Maps staged to LDS SoA; scoreOf is
// LDS-only; phase-2 resample uses all 256 threads (c = t).
__global__ __launch_bounds__(256) void warp_kernel(const float* __restrict__ uv,
        const float* __restrict__ latent, const float* __restrict__ ls,
        float* __restrict__ out, const float* __restrict__ ref_pm,
        const double* __restrict__ maps) {
    const int b   = blockIdx.x;
    const int wg  = (b & 7) * 384 + (b >> 3);   // XCD swizzle (3072 = 8*384, bijective)
    const int sb  = wg / ((NV - 1) * N);
    const int rem = wg % ((NV - 1) * N);
    const int v   = rem / N;
    const int n   = rem % N;
    const int imC = sb * 3 + v;
    const int t   = threadIdx.x;
    const int wv  = t >> 6, ln = t & 63;
    const int r   = ln >> 2, q = ln & 3;

    __shared__ double sS2[256], sSH[256], sSV[256], sSD[256], sSA[256];  // map SoA
    __shared__ double partR[4][64][4];
    __shared__ double mRl[PS * 17];   // [16][17] padded
    __shared__ int    kselS;

    const float ls0 = ls[0], ls1 = ls[1];
    const float sx = ls0 / IMG, sy = ls1 / IMG;
    const float2 uvp = reinterpret_cast<const float2*>(uv)[(sb * NV + 1 + v) * N + n];
    const float uvnx = uvp.x * sx - 1.0f;
    const float uvny = uvp.y * sy - 1.0f;
    const float txc = fminf(fmaxf((uvnx + 1.0f) * 0.5f * (float)(W - 1), 0.0f), (float)(W - 1));
    const float tyc = fminf(fmaxf((uvny + 1.0f) * 0.5f * (float)(H - 1), 0.0f), (float)(H - 1));
    const int ox = (int)floorf(txc) - 6;
    const int oy = (int)floorf(tyc) - 6;

    const float*  lat  = latent + (size_t)(sb * NV + 1 + v) * L * HW;
    const double* mimg = maps + (size_t)imC * HW * MAPST;

    // Stage the 16x16 window's point-invariant records into LDS (SoA).
    {
        const int wy_ = t >> 4, wx_ = t & 15;
        const int gyr = min(max(oy + wy_, 0), H - 1);
        const int gxr = min(max(ox + wx_, 0), W - 1);
        const double* rec = mimg + (size_t)(gyr * W + gxr) * MAPST;
        sS2[t] = rec[0]; sSH[t] = rec[1]; sSV[t] = rec[2]; sSD[t] = rec[3]; sSA[t] = rec[4];
    }

    // R-partials: this wave's 64 channels.
    const float* refp = ref_pm + (size_t)(sb * N + n) * L + wv * 64;
    const int gy = min(max(oy + r, 0), H - 1);      // border-clamped row
    const int cb = ox + 4 * q;
    const bool fast = (ox >= 0) && (ox + PS <= W);
    const int gx0 = min(max(cb + 0, 0), W - 1);
    const int gx1 = min(max(cb + 1, 0), W - 1);
    const int gx2 = min(max(cb + 2, 0), W - 1);
    const int gx3 = min(max(cb + 3, 0), W - 1);
    const float* rowp = lat + (size_t)wv * 64 * HW + (size_t)gy * W;

    double aR[4] = {0, 0, 0, 0};
    if (fast) {
        const float* pbase = rowp + cb;
        #pragma unroll 4
        for (int c = 0; c < 64; ++c) {
            const f4v p = *reinterpret_cast<const f4v*>(pbase + (size_t)c * HW);
            const double rf = (double)refp[c];
            aR[0] = fma(rf, (double)p.x, aR[0]);
            aR[1] = fma(rf, (double)p.y, aR[1]);
            aR[2] = fma(rf, (double)p.z, aR[2]);
            aR[3] = fma(rf, (double)p.w, aR[3]);
        }
    } else {
        #pragma unroll 4
        for (int c = 0; c < 64; ++c) {
            const float* chp = rowp + (size_t)c * HW;
            const double rf = (double)refp[c];
            aR[0] = fma(rf, (double)chp[gx0], aR[0]);
            aR[1] = fma(rf, (double)chp[gx1], aR[1]);
            aR[2] = fma(rf, (double)chp[gx2], aR[2]);
            aR[3] = fma(rf, (double)chp[gx3], aR[3]);
        }
    }
    partR[wv][ln][0] = aR[0]; partR[wv][ln][1] = aR[1];
    partR[wv][ln][2] = aR[2]; partR[wv][ln][3] = aR[3];
    __syncthreads();

    if (wv == 0) {
        // Fixed-order reduce (p0+p1)+p2)+p3 -> final R for this lane's 4 cols.
        const int mi = r * 17 + 4 * q;
        #pragma unroll
        for (int j = 0; j < 4; ++j) {
            mRl[mi + j] = ((partR[0][ln][j] + partR[1][ln][j]) + partR[2][ln][j]) + partR[3][ln][j];
        }

        auto scoreOf = [&](int k) -> double {
            const int i = k / NP, j = k % NP;          // i -> x offset, j -> y offset
            const float gpx = ((float)(i - PAD) / (float)W) * ls0;
            const float gpy = ((float)(j - PAD) / (float)H) * ls1;
            int x0, x1, y0, y1; float wx, wy;
            coord1(uvnx + gpx, W, x0, x1, wx);
            coord1(uvny + gpy, H, y0, y1, wy);
            const int cx0 = min(max(x0 - ox, 0), 15), cx1 = min(max(x1 - ox, 0), 15);
            const int cy0 = min(max(y0 - oy, 0), 15), cy1 = min(max(y1 - oy, 0), 15);
            const double R00 = mRl[cy0 * 17 + cx0], R01 = mRl[cy0 * 17 + cx1];
            const double R10 = mRl[cy1 * 17 + cx0], R11 = mRl[cy1 * 17 + cx1];
            const int p00 = cy0 * 16 + cx0, p01 = cy0 * 16 + cx1;
            const int p10 = cy1 * 16 + cx0, p11 = cy1 * 16 + cx1;
            const double dwx = (double)wx, dwy = (double)wy;
            const double Aw = (1.0 - dwy) * (1.0 - dwx), Bw = (1.0 - dwy) * dwx;
            const double Cw = dwy * (1.0 - dwx),         Dw = dwy * dwx;
            const double num = (1.0 - dwy) * ((1.0 - dwx) * R00 + dwx * R01)
                             +        dwy  * ((1.0 - dwx) * R10 + dwx * R11);
            double nrm = Aw * Aw * sS2[p00] + Bw * Bw * sS2[p01]
                       + Cw * Cw * sS2[p10] + Dw * Dw * sS2[p11]
                       + 2.0 * (Aw * Bw * sSH[p00] + Cw * Dw * sSH[p10]
                              + Aw * Cw * sSV[p00] + Bw * Dw * sSV[p01]
                              + Aw * Dw * sSD[p00] + Bw * Cw * sSA[p00]);
            nrm = fmax(nrm, 0.0);
            return num / fmax(sqrt(nrm), 1.0e-8);      // ref-norm: positive per-point constant
        };

        double bs = scoreOf(ln);                        // lanes 0..63 all < K
        int    bi = ln;
        if (ln + 64 < K) {
            const double s2 = scoreOf(ln + 64);
            if (s2 > bs) { bs = s2; bi = ln + 64; }     // strict >: smaller k wins ties
        }
        #pragma unroll
        for (int d = 1; d < 64; d <<= 1) {
            const double so = __shfl_xor(bs, d, 64);
            const int    io = __shfl_xor(bi, d, 64);
            if (so > bs || (so == bs && io < bi)) { bs = so; bi = io; }
        }
        if (ln == 0) kselS = bi;
    }
    __syncthreads();
    const int ksel = kselS;

    // Phase 2: exact reference resample of the winner; thread t = channel t.
    const int si = ksel / NP, sj = ksel % NP;
    const float gpx = ((float)(si - PAD) / (float)W) * ls0;
    const float gpy = ((float)(sj - PAD) / (float)H) * ls1;
    int x0, x1, y0, y1; float wx, wy;
    coord1(uvnx + gpx, W, x0, x1, wx);
    coord1(uvny + gpy, H, y0, y1, wy);
    float* o = out + (size_t)((sb * NV + 1 + v) * L) * N + n;
    if (x0 + 1 < W) {                              // block-uniform fast path
        const f2v tv = *reinterpret_cast<const f2v*>(lat + (size_t)t * HW + y0 * W + x0);
        const f2v bv = *reinterpret_cast<const f2v*>(lat + (size_t)t * HW + y1 * W + x0);
        const float top = tv.x * (1.0f - wx) + tv.y * wx;
        const float bot = bv.x * (1.0f - wx) + bv.y * wx;
        o[(size_t)t * N] = top * (1.0f - wy) + bot * wy;
    } else {
        const float* ch = lat + (size_t)t * HW;
        const float v00 = ch[y0 * W + x0], v01 = ch[y0 * W + x1];
        const float v10 = ch[y1 * W + x0], v11 = ch[y1 * W + x1];
        const float top = v00 * (1.0f - wx) + v01 * wx;
        const float bot = v10 * (1.0f - wx) + v11 * wx;
        o[(size_t)t * N] = top * (1.0f - wy) + bot * wy;
    }
}

} // namespace

extern "C" void kernel_launch(void* const* d_in, const int* in_sizes, int n_in,
                              void* d_out, int out_size, void* d_ws, size_t ws_size,
                              hipStream_t stream) {
    const float* uv     = (const float*)d_in[0];
    const float* latent = (const float*)d_in[1];
    const float* ls     = (const float*)d_in[2];
    float* out    = (float*)d_out;
    float* ref_pm = (float*)d_ws;                                   // 1 MB
    double* maps  = (double*)((char*)d_ws + (1 << 20));             // 6*16384*64B = 6.3 MB

    hipLaunchKernelGGL(map_kernel, dim3(6 * H), dim3(256), 0, stream, latent, maps);
    hipLaunchKernelGGL(ref_kernel, dim3(SB * N), dim3(64), 0, stream, uv, latent, ls, out, ref_pm);
    hipLaunchKernelGGL(warp_kernel, dim3(SB * (NV - 1) * N), dim3(256), 0, stream,
                       uv, latent, ls, out, ref_pm, maps);
}